// Round 5
// baseline (67.704 us; speedup 1.0000x reference)
//
#include <hip/hip_runtime.h>
#include <math.h>

// Problem constants (from reference setup_inputs)
constexpr int B_ = 8, N_ = 32768, CAT_ = 128, FEAT_ = 128, K_ = 64;
constexpr float DELTA_ = 0.5f;

typedef __bf16 bf16x8 __attribute__((ext_vector_type(8)));
typedef float f32x4 __attribute__((ext_vector_type(4)));

constexpr int GEMM_BLOCKS = (B_ * N_) / 128;  // 2048 (128 n-rows per block)

// ---------------------------------------------------------------------------
// prep: builds bf16 W^T [FEAT][CAT], XOR-swizzled within each row
// (wT_swz[f][c ^ ((f&7)<<3)] = w[c][f]) so that a LINEAR global_load_lds copy
// yields a swizzled LDS image (G21: pre-swizzled source + swizzled read).
// Also produces new_weight (copy + broadcast L2-norm rows).
// grid = CAT_ blocks x FEAT_ threads.
// ---------------------------------------------------------------------------
__global__ void prep_kernel(const float* __restrict__ weight,
                            const int* __restrict__ keys,
                            const float* __restrict__ values,
                            float* __restrict__ outw,    // [CAT][FEAT]
                            __bf16* __restrict__ wTs)    // [FEAT][CAT] swizzled
{
    const int r = blockIdx.x;    // weight row (CAT index = c)
    const int t = threadIdx.x;   // FEAT index (f)
    float w = weight[r * FEAT_ + t];
    wTs[t * CAT_ + (r ^ ((t & 7) << 3))] = (__bf16)w;

    bool keyed = false;
    for (int i = 0; i < K_; ++i) keyed |= (keys[i] == r);
    if (!keyed) outw[r * FEAT_ + t] = w;

    if (r < K_ && t < 64) {
        const int key = keys[r];
        float a0 = DELTA_ * weight[key * FEAT_ + t]      + (1.0f - DELTA_) * values[r * FEAT_ + t];
        float a1 = DELTA_ * weight[key * FEAT_ + t + 64] + (1.0f - DELTA_) * values[r * FEAT_ + t + 64];
        float ss = a0 * a0 + a1 * a1;
        #pragma unroll
        for (int off = 32; off > 0; off >>= 1)
            ss += __shfl_down(ss, off, 64);
        float nrm = sqrtf(__shfl(ss, 0, 64));
        outw[key * FEAT_ + t]      = nrm;
        outw[key * FEAT_ + t + 64] = nrm;
    }
}

// ---------------------------------------------------------------------------
// gemm: out[b][f][n] = sum_c input[b][n][c] * w[c][f]
//  - wT_swz staged to LDS via global_load_lds_dwordx4 (linear, no converts)
//  - all 16 input f32x4 loads ISSUED and PINNED above the barrier via
//    sched_barrier(0) (a plain __syncthreads does not order global loads;
//    R4's VGPR_Count=64 proved the compiler sank them into the loop)
//  - weight frags via swizzled ds_read_b128
//  - swapped mfma operands: A=input, B=weight -> D's 4 regs/lane are 4
//    consecutive n at fixed f -> plain dwordx4 stores (L2-allocating;
//    nontemporal refuted in R4: +22% WRITE_SIZE, no FETCH change)
// ---------------------------------------------------------------------------
__global__ __launch_bounds__(256, 4) void gemm_kernel(
    const float* __restrict__ input,   // [B][N][CAT]
    const __bf16* __restrict__ wTs,    // [FEAT][CAT] bf16, swizzled
    float* __restrict__ out)           // [B][FEAT][N]
{
    __shared__ __bf16 wt[FEAT_ * CAT_];  // 32 KB, linear copy of wTs (already swizzled)

    const int tid  = threadIdx.x;
    const int wid  = tid >> 6;
    const int lane = tid & 63;

    // stage wT_swz -> LDS: 8 iters x (64 lanes x 16B) per wave = 32 KB total
    #pragma unroll
    for (int j = 0; j < 8; ++j) {
        int off = j * 4096 + wid * 1024;  // bytes; wave-uniform LDS base
        __builtin_amdgcn_global_load_lds(
            (const __attribute__((address_space(1))) void*)((const char*)wTs + off + lane * 16),
            (__attribute__((address_space(3))) void*)((char*)wt + off),
            16, 0, 0);
    }

    const int qlo = lane & 15;   // fragment row/col index
    const int qhi = lane >> 4;   // 0..3, selects k-group of 8
    const int bid = blockIdx.x;
    const int b   = bid >> 8;
    const int nb  = bid & 255;
    const int n0  = nb * 128 + wid * 32;

    // issue the wave's ENTIRE input tile; pin above the barrier
    const float* in_base = input + ((size_t)b * N_ + n0) * CAT_;
    f32x4 ibuf[4][2][2];
    #pragma unroll
    for (int ck = 0; ck < 4; ++ck)
        #pragma unroll
        for (int nt = 0; nt < 2; ++nt) {
            const float* p = in_base + (size_t)(nt * 16 + qlo) * CAT_ + ck * 32 + qhi * 8;
            ibuf[ck][nt][0] = *(const f32x4*)p;
            ibuf[ck][nt][1] = *(const f32x4*)(p + 4);
        }
    __builtin_amdgcn_sched_barrier(0);  // keep the loads issued up here

    f32x4 acc[8][2];
    #pragma unroll
    for (int i = 0; i < 8; ++i)
        #pragma unroll
        for (int j = 0; j < 2; ++j)
            acc[i][j] = (f32x4)0.0f;

    __syncthreads();

    #pragma unroll
    for (int ck = 0; ck < 4; ++ck) {
        bf16x8 bfrag[2];  // input fragments (MFMA A operand)
        #pragma unroll
        for (int nt = 0; nt < 2; ++nt) {
            bf16x8 t;
            #pragma unroll
            for (int e = 0; e < 4; ++e) {
                t[e]     = (__bf16)ibuf[ck][nt][0][e];
                t[e + 4] = (__bf16)ibuf[ck][nt][1][e];
            }
            bfrag[nt] = t;
        }
        const int cswz = (ck * 32 + qhi * 8) ^ ((qlo & 7) << 3);  // swizzled c-offset
        #pragma unroll
        for (int mt = 0; mt < 8; ++mt) {
            bf16x8 af = *(const bf16x8*)&wt[(mt * 16 + qlo) * CAT_ + cswz];
            // swapped operands: D[n][f]
            acc[mt][0] = __builtin_amdgcn_mfma_f32_16x16x32_bf16(bfrag[0], af, acc[mt][0], 0, 0, 0);
            acc[mt][1] = __builtin_amdgcn_mfma_f32_16x16x32_bf16(bfrag[1], af, acc[mt][1], 0, 0, 0);
        }
    }

    // epilogue: D col=lane&15 -> f-in-tile, row=(lane>>4)*4+r -> n-in-tile.
    // Each lane: 4 consecutive n at fixed f -> one plain dwordx4 per tile.
    float* outp = out + (size_t)b * FEAT_ * N_;
    #pragma unroll
    for (int mt = 0; mt < 8; ++mt) {
        #pragma unroll
        for (int nt = 0; nt < 2; ++nt) {
            size_t off = (size_t)(mt * 16 + qlo) * N_ + (size_t)(n0 + nt * 16 + qhi * 4);
            *(f32x4*)(outp + off) = acc[mt][nt];
        }
    }
}

// ---------------------------------------------------------------------------
// Fallback (R1 kernel): single launch with per-block LDS staging, used only
// if the workspace is too small for wT_swz.
// ---------------------------------------------------------------------------
constexpr int LDSTR = 136;

__global__ __launch_bounds__(256, 4) void ocm_fused(
    const float* __restrict__ input,
    const float* __restrict__ weight,
    const int* __restrict__ keys,
    const float* __restrict__ values,
    float* __restrict__ out)
{
    const int bid = blockIdx.x;
    const int tid = threadIdx.x;

    if (bid >= GEMM_BLOCKS) {
        float* outw = out + (size_t)B_ * FEAT_ * N_;
        const int r = bid - GEMM_BLOCKS;
        bool keyed = false;
        for (int i = 0; i < K_; ++i) keyed |= (keys[i] == r);
        if (!keyed && tid < FEAT_)
            outw[r * FEAT_ + tid] = weight[r * FEAT_ + tid];
        if (r < K_ && tid < 64) {
            const int key = keys[r];
            float a0 = DELTA_ * weight[key * FEAT_ + tid]      + (1.0f - DELTA_) * values[r * FEAT_ + tid];
            float a1 = DELTA_ * weight[key * FEAT_ + tid + 64] + (1.0f - DELTA_) * values[r * FEAT_ + tid + 64];
            float ss = a0 * a0 + a1 * a1;
            #pragma unroll
            for (int off = 32; off > 0; off >>= 1)
                ss += __shfl_down(ss, off, 64);
            float nrm = sqrtf(__shfl(ss, 0, 64));
            outw[key * FEAT_ + tid]      = nrm;
            outw[key * FEAT_ + tid + 64] = nrm;
        }
        return;
    }

    __shared__ __bf16 wt[FEAT_ * LDSTR];
    #pragma unroll
    for (int j = 0; j < (CAT_ * FEAT_) / 256; ++j) {
        int i = tid + j * 256;
        int c = i >> 7;
        int f = i & (FEAT_ - 1);
        wt[f * LDSTR + c] = (__bf16)weight[i];
    }
    __syncthreads();

    const int wid  = tid >> 6;
    const int lane = tid & 63;
    const int qlo  = lane & 15;
    const int qhi  = lane >> 4;
    const int b    = bid >> 8;
    const int nb   = bid & 255;
    const int n0   = nb * 128 + wid * 32;

    f32x4 acc[8][2];
    #pragma unroll
    for (int i = 0; i < 8; ++i)
        #pragma unroll
        for (int j = 0; j < 2; ++j)
            acc[i][j] = (f32x4)0.0f;

    const float* in_base = input + ((size_t)b * N_ + n0) * CAT_;

    #pragma unroll
    for (int ck = 0; ck < 4; ++ck) {
        bf16x8 bfrag[2];
        #pragma unroll
        for (int nt = 0; nt < 2; ++nt) {
            const float* p = in_base + (size_t)(nt * 16 + qlo) * CAT_ + ck * 32 + qhi * 8;
            f32x4 v0 = *(const f32x4*)p;
            f32x4 v1 = *(const f32x4*)(p + 4);
            bf16x8 t;
            t[0] = (__bf16)v0[0]; t[1] = (__bf16)v0[1]; t[2] = (__bf16)v0[2]; t[3] = (__bf16)v0[3];
            t[4] = (__bf16)v1[0]; t[5] = (__bf16)v1[1]; t[6] = (__bf16)v1[2]; t[7] = (__bf16)v1[3];
            bfrag[nt] = t;
        }
        #pragma unroll
        for (int mt = 0; mt < 8; ++mt) {
            bf16x8 afrag = *(const bf16x8*)&wt[(mt * 16 + qlo) * LDSTR + ck * 32 + qhi * 8];
            acc[mt][0] = __builtin_amdgcn_mfma_f32_16x16x32_bf16(afrag, bfrag[0], acc[mt][0], 0, 0, 0);
            acc[mt][1] = __builtin_amdgcn_mfma_f32_16x16x32_bf16(afrag, bfrag[1], acc[mt][1], 0, 0, 0);
        }
    }

    float* outp = out + (size_t)b * FEAT_ * N_ + n0;
    #pragma unroll
    for (int mt = 0; mt < 8; ++mt) {
        #pragma unroll
        for (int nt = 0; nt < 2; ++nt) {
            #pragma unroll
            for (int r = 0; r < 4; ++r) {
                int f = mt * 16 + qhi * 4 + r;
                outp[(size_t)f * N_ + nt * 16 + qlo] = acc[mt][nt][r];
            }
        }
    }
}

extern "C" void kernel_launch(void* const* d_in, const int* in_sizes, int n_in,
                              void* d_out, int out_size, void* d_ws, size_t ws_size,
                              hipStream_t stream) {
    const float* input  = (const float*)d_in[0];
    const float* weight = (const float*)d_in[1];
    const int*   keys   = (const int*)d_in[2];
    const float* values = (const float*)d_in[3];
    float* out = (float*)d_out;

    if (ws_size >= (size_t)CAT_ * FEAT_ * sizeof(__bf16)) {
        __bf16* wTs = (__bf16*)d_ws;
        float* outw = out + (size_t)B_ * FEAT_ * N_;
        prep_kernel<<<CAT_, FEAT_, 0, stream>>>(weight, keys, values, outw, wTs);
        gemm_kernel<<<GEMM_BLOCKS, 256, 0, stream>>>(input, wTs, out);
    } else {
        ocm_fused<<<GEMM_BLOCKS + CAT_, 256, 0, stream>>>(input, weight, keys, values, out);
    }
}

// Round 6
// 55.186 us; speedup vs baseline: 1.2268x; 1.2268x over previous
//
#include <hip/hip_runtime.h>
#include <math.h>

// Problem constants (from reference setup_inputs)
constexpr int B_ = 8, N_ = 32768, CAT_ = 128, FEAT_ = 128, K_ = 64;
constexpr float DELTA_ = 0.5f;

typedef __bf16 bf16x8 __attribute__((ext_vector_type(8)));
typedef float f32x4 __attribute__((ext_vector_type(4)));

constexpr int GEMM_BLOCKS = (B_ * N_) / 128;  // 2048 (128 n-rows per block)

// ---------------------------------------------------------------------------
// prep: builds bf16 W^T [FEAT][CAT], XOR-swizzled within each row
// (wT_swz[f][c ^ ((f&7)<<3)] = w[c][f]) so that a LINEAR global_load_lds copy
// yields a swizzled LDS image (G21: pre-swizzled source + swizzled read).
// Also produces new_weight (copy + broadcast L2-norm rows).
// grid = CAT_ blocks x FEAT_ threads.
// ---------------------------------------------------------------------------
__global__ void prep_kernel(const float* __restrict__ weight,
                            const int* __restrict__ keys,
                            const float* __restrict__ values,
                            float* __restrict__ outw,    // [CAT][FEAT]
                            __bf16* __restrict__ wTs)    // [FEAT][CAT] swizzled
{
    const int r = blockIdx.x;    // weight row (CAT index = c)
    const int t = threadIdx.x;   // FEAT index (f)
    float w = weight[r * FEAT_ + t];
    wTs[t * CAT_ + (r ^ ((t & 7) << 3))] = (__bf16)w;

    bool keyed = false;
    for (int i = 0; i < K_; ++i) keyed |= (keys[i] == r);
    if (!keyed) outw[r * FEAT_ + t] = w;

    if (r < K_ && t < 64) {
        const int key = keys[r];
        float a0 = DELTA_ * weight[key * FEAT_ + t]      + (1.0f - DELTA_) * values[r * FEAT_ + t];
        float a1 = DELTA_ * weight[key * FEAT_ + t + 64] + (1.0f - DELTA_) * values[r * FEAT_ + t + 64];
        float ss = a0 * a0 + a1 * a1;
        #pragma unroll
        for (int off = 32; off > 0; off >>= 1)
            ss += __shfl_down(ss, off, 64);
        float nrm = sqrtf(__shfl(ss, 0, 64));
        outw[key * FEAT_ + t]      = nrm;
        outw[key * FEAT_ + t + 64] = nrm;
    }
}

// ---------------------------------------------------------------------------
// gemm: out[b][f][n] = sum_c input[b][n][c] * w[c][f]   (R3 structure)
//  - wT_swz staged to LDS via global_load_lds_dwordx4 (linear, no converts)
//  - all 16 input f32x4 loads issued up front and PINNED via keep-alive
//    asm volatile (rule #17): loads cannot sink past an asm consuming their
//    results. One vmcnt drain (shared with the staging drain at the barrier),
//    then the ck-loop is pure LDS+cvt+MFMA with no global waits.
//    R4/R5 evidence: sched_barrier(0) does NOT achieve this (VGPR stayed 64).
//  - weight frags via swizzled ds_read_b128 (conflict-floor)
// ---------------------------------------------------------------------------
__global__ __launch_bounds__(256, 4) void gemm_kernel(
    const float* __restrict__ input,   // [B][N][CAT]
    const __bf16* __restrict__ wTs,    // [FEAT][CAT] bf16, swizzled
    float* __restrict__ out)           // [B][FEAT][N]
{
    __shared__ __bf16 wt[FEAT_ * CAT_];  // 32 KB, linear copy of wTs (already swizzled)

    const int tid  = threadIdx.x;
    const int wid  = tid >> 6;
    const int lane = tid & 63;

    // stage wT_swz -> LDS: 8 iters x (64 lanes x 16B) per wave = 32 KB total
    #pragma unroll
    for (int j = 0; j < 8; ++j) {
        int off = j * 4096 + wid * 1024;  // bytes; wave-uniform LDS base
        __builtin_amdgcn_global_load_lds(
            (const __attribute__((address_space(1))) void*)((const char*)wTs + off + lane * 16),
            (__attribute__((address_space(3))) void*)((char*)wt + off),
            16, 0, 0);
    }

    const int qlo = lane & 15;   // MFMA col / A row index
    const int qhi = lane >> 4;   // 0..3, selects k-group of 8
    const int bid = blockIdx.x;
    const int b   = bid >> 8;
    const int nb  = bid & 255;
    const int n0  = nb * 128 + wid * 32;

    // issue the wave's ENTIRE input tile, then pin it live with asm
    const float* in_base = input + ((size_t)b * N_ + n0) * CAT_;
    f32x4 ibuf[4][2][2];
    #pragma unroll
    for (int ck = 0; ck < 4; ++ck)
        #pragma unroll
        for (int nt = 0; nt < 2; ++nt) {
            const float* p = in_base + (size_t)(nt * 16 + qlo) * CAT_ + ck * 32 + qhi * 8;
            ibuf[ck][nt][0] = *(const f32x4*)p;
            ibuf[ck][nt][1] = *(const f32x4*)(p + 4);
        }
    // keep-alive: forces all 16 loads to be issued and their results held in
    // VGPRs here (compiler cannot sink a load past an asm reading its result)
    #pragma unroll
    for (int ck = 0; ck < 4; ++ck)
        #pragma unroll
        for (int nt = 0; nt < 2; ++nt)
            asm volatile("" :: "v"(ibuf[ck][nt][0]), "v"(ibuf[ck][nt][1]));

    f32x4 acc[8][2];
    #pragma unroll
    for (int i = 0; i < 8; ++i)
        #pragma unroll
        for (int j = 0; j < 2; ++j)
            acc[i][j] = (f32x4)0.0f;

    __syncthreads();

    #pragma unroll
    for (int ck = 0; ck < 4; ++ck) {
        bf16x8 bfrag[2];
        #pragma unroll
        for (int nt = 0; nt < 2; ++nt) {
            bf16x8 t;
            #pragma unroll
            for (int e = 0; e < 4; ++e) {
                t[e]     = (__bf16)ibuf[ck][nt][0][e];
                t[e + 4] = (__bf16)ibuf[ck][nt][1][e];
            }
            bfrag[nt] = t;
        }
        const int cswz = (ck * 32 + qhi * 8) ^ ((qlo & 7) << 3);  // swizzled c-offset
        #pragma unroll
        for (int mt = 0; mt < 8; ++mt) {
            bf16x8 af = *(const bf16x8*)&wt[(mt * 16 + qlo) * CAT_ + cswz];
            acc[mt][0] = __builtin_amdgcn_mfma_f32_16x16x32_bf16(af, bfrag[0], acc[mt][0], 0, 0, 0);
            acc[mt][1] = __builtin_amdgcn_mfma_f32_16x16x32_bf16(af, bfrag[1], acc[mt][1], 0, 0, 0);
        }
    }

    // epilogue: C/D layout col=lane&15 -> n, row=(lane>>4)*4+reg -> f (m89/m91)
    float* outp = out + (size_t)b * FEAT_ * N_ + n0;
    #pragma unroll
    for (int mt = 0; mt < 8; ++mt) {
        #pragma unroll
        for (int nt = 0; nt < 2; ++nt) {
            #pragma unroll
            for (int r = 0; r < 4; ++r) {
                int f = mt * 16 + qhi * 4 + r;
                outp[(size_t)f * N_ + nt * 16 + qlo] = acc[mt][nt][r];
            }
        }
    }
}

// ---------------------------------------------------------------------------
// Fallback (R1 kernel): single launch with per-block LDS staging, used only
// if the workspace is too small for wT_swz.
// ---------------------------------------------------------------------------
constexpr int LDSTR = 136;

__global__ __launch_bounds__(256, 4) void ocm_fused(
    const float* __restrict__ input,
    const float* __restrict__ weight,
    const int* __restrict__ keys,
    const float* __restrict__ values,
    float* __restrict__ out)
{
    const int bid = blockIdx.x;
    const int tid = threadIdx.x;

    if (bid >= GEMM_BLOCKS) {
        float* outw = out + (size_t)B_ * FEAT_ * N_;
        const int r = bid - GEMM_BLOCKS;
        bool keyed = false;
        for (int i = 0; i < K_; ++i) keyed |= (keys[i] == r);
        if (!keyed && tid < FEAT_)
            outw[r * FEAT_ + tid] = weight[r * FEAT_ + tid];
        if (r < K_ && tid < 64) {
            const int key = keys[r];
            float a0 = DELTA_ * weight[key * FEAT_ + tid]      + (1.0f - DELTA_) * values[r * FEAT_ + tid];
            float a1 = DELTA_ * weight[key * FEAT_ + tid + 64] + (1.0f - DELTA_) * values[r * FEAT_ + tid + 64];
            float ss = a0 * a0 + a1 * a1;
            #pragma unroll
            for (int off = 32; off > 0; off >>= 1)
                ss += __shfl_down(ss, off, 64);
            float nrm = sqrtf(__shfl(ss, 0, 64));
            outw[key * FEAT_ + tid]      = nrm;
            outw[key * FEAT_ + tid + 64] = nrm;
        }
        return;
    }

    __shared__ __bf16 wt[FEAT_ * LDSTR];
    #pragma unroll
    for (int j = 0; j < (CAT_ * FEAT_) / 256; ++j) {
        int i = tid + j * 256;
        int c = i >> 7;
        int f = i & (FEAT_ - 1);
        wt[f * LDSTR + c] = (__bf16)weight[i];
    }
    __syncthreads();

    const int wid  = tid >> 6;
    const int lane = tid & 63;
    const int qlo  = lane & 15;
    const int qhi  = lane >> 4;
    const int b    = bid >> 8;
    const int nb   = bid & 255;
    const int n0   = nb * 128 + wid * 32;

    f32x4 acc[8][2];
    #pragma unroll
    for (int i = 0; i < 8; ++i)
        #pragma unroll
        for (int j = 0; j < 2; ++j)
            acc[i][j] = (f32x4)0.0f;

    const float* in_base = input + ((size_t)b * N_ + n0) * CAT_;

    #pragma unroll
    for (int ck = 0; ck < 4; ++ck) {
        bf16x8 bfrag[2];
        #pragma unroll
        for (int nt = 0; nt < 2; ++nt) {
            const float* p = in_base + (size_t)(nt * 16 + qlo) * CAT_ + ck * 32 + qhi * 8;
            f32x4 v0 = *(const f32x4*)p;
            f32x4 v1 = *(const f32x4*)(p + 4);
            bf16x8 t;
            t[0] = (__bf16)v0[0]; t[1] = (__bf16)v0[1]; t[2] = (__bf16)v0[2]; t[3] = (__bf16)v0[3];
            t[4] = (__bf16)v1[0]; t[5] = (__bf16)v1[1]; t[6] = (__bf16)v1[2]; t[7] = (__bf16)v1[3];
            bfrag[nt] = t;
        }
        #pragma unroll
        for (int mt = 0; mt < 8; ++mt) {
            bf16x8 afrag = *(const bf16x8*)&wt[(mt * 16 + qlo) * LDSTR + ck * 32 + qhi * 8];
            acc[mt][0] = __builtin_amdgcn_mfma_f32_16x16x32_bf16(afrag, bfrag[0], acc[mt][0], 0, 0, 0);
            acc[mt][1] = __builtin_amdgcn_mfma_f32_16x16x32_bf16(afrag, bfrag[1], acc[mt][1], 0, 0, 0);
        }
    }

    float* outp = out + (size_t)b * FEAT_ * N_ + n0;
    #pragma unroll
    for (int mt = 0; mt < 8; ++mt) {
        #pragma unroll
        for (int nt = 0; nt < 2; ++nt) {
            #pragma unroll
            for (int r = 0; r < 4; ++r) {
                int f = mt * 16 + qhi * 4 + r;
                outp[(size_t)f * N_ + nt * 16 + qlo] = acc[mt][nt][r];
            }
        }
    }
}

extern "C" void kernel_launch(void* const* d_in, const int* in_sizes, int n_in,
                              void* d_out, int out_size, void* d_ws, size_t ws_size,
                              hipStream_t stream) {
    const float* input  = (const float*)d_in[0];
    const float* weight = (const float*)d_in[1];
    const int*   keys   = (const int*)d_in[2];
    const float* values = (const float*)d_in[3];
    float* out = (float*)d_out;

    if (ws_size >= (size_t)CAT_ * FEAT_ * sizeof(__bf16)) {
        __bf16* wTs = (__bf16*)d_ws;
        float* outw = out + (size_t)B_ * FEAT_ * N_;
        prep_kernel<<<CAT_, FEAT_, 0, stream>>>(weight, keys, values, outw, wTs);
        gemm_kernel<<<GEMM_BLOCKS, 256, 0, stream>>>(input, wTs, out);
    } else {
        ocm_fused<<<GEMM_BLOCKS + CAT_, 256, 0, stream>>>(input, weight, keys, values, out);
    }
}

// Round 7
// 53.774 us; speedup vs baseline: 1.2590x; 1.0263x over previous
//
#include <hip/hip_runtime.h>
#include <math.h>

// Problem constants (from reference setup_inputs)
constexpr int B_ = 8, N_ = 32768, CAT_ = 128, FEAT_ = 128, K_ = 64;
constexpr float DELTA_ = 0.5f;

typedef __bf16 bf16x8 __attribute__((ext_vector_type(8)));
typedef float f32x4 __attribute__((ext_vector_type(4)));

constexpr int BLOCK = 512;                       // 8 waves share one weight tile
constexpr int NPB   = 256;                       // n-rows per block (32 per wave)
constexpr int GEMM_BLOCKS = (B_ * N_) / NPB;     // 1024

// ---------------------------------------------------------------------------
// prep: builds bf16 W^T [FEAT][CAT], XOR-swizzled within each row
// (wT_swz[f][c ^ ((f&7)<<3)] = w[c][f]) so that a LINEAR global_load_lds copy
// yields a swizzled LDS image (G21: pre-swizzled source + swizzled read).
// Also produces new_weight (copy + broadcast L2-norm rows).
// grid = CAT_ blocks x FEAT_ threads.
// ---------------------------------------------------------------------------
__global__ void prep_kernel(const float* __restrict__ weight,
                            const int* __restrict__ keys,
                            const float* __restrict__ values,
                            float* __restrict__ outw,    // [CAT][FEAT]
                            __bf16* __restrict__ wTs)    // [FEAT][CAT] swizzled
{
    const int r = blockIdx.x;    // weight row (CAT index = c)
    const int t = threadIdx.x;   // FEAT index (f)
    float w = weight[r * FEAT_ + t];
    wTs[t * CAT_ + (r ^ ((t & 7) << 3))] = (__bf16)w;

    bool keyed = false;
    for (int i = 0; i < K_; ++i) keyed |= (keys[i] == r);
    if (!keyed) outw[r * FEAT_ + t] = w;

    if (r < K_ && t < 64) {
        const int key = keys[r];
        float a0 = DELTA_ * weight[key * FEAT_ + t]      + (1.0f - DELTA_) * values[r * FEAT_ + t];
        float a1 = DELTA_ * weight[key * FEAT_ + t + 64] + (1.0f - DELTA_) * values[r * FEAT_ + t + 64];
        float ss = a0 * a0 + a1 * a1;
        #pragma unroll
        for (int off = 32; off > 0; off >>= 1)
            ss += __shfl_down(ss, off, 64);
        float nrm = sqrtf(__shfl(ss, 0, 64));
        outw[key * FEAT_ + t]      = nrm;
        outw[key * FEAT_ + t + 64] = nrm;
    }
}

// ---------------------------------------------------------------------------
// gemm: out[b][f][n] = sum_c input[b][n][c] * w[c][f]   (R3 structure, 512 thr)
//  - 8 waves share ONE 32KB LDS weight tile -> LDS/thread halves ->
//    occupancy cap goes from ~3 blocks (12 waves) to 32 waves/CU.
//  - wT_swz staged via global_load_lds_dwordx4 (linear, no converts)
//  - weight frags via swizzled ds_read_b128 (conflict-floor)
//  - input loads live in the ck-loop (R4-R6: compiler sinks/remats any
//    attempted prefetch; occupancy is the latency-hiding mechanism instead)
// ---------------------------------------------------------------------------
__global__ __launch_bounds__(BLOCK, 4) void gemm_kernel(
    const float* __restrict__ input,   // [B][N][CAT]
    const __bf16* __restrict__ wTs,    // [FEAT][CAT] bf16, swizzled
    float* __restrict__ out)           // [B][FEAT][N]
{
    __shared__ __bf16 wt[FEAT_ * CAT_];  // 32 KB, linear copy of wTs (already swizzled)

    const int tid  = threadIdx.x;
    const int wid  = tid >> 6;           // 0..7
    const int lane = tid & 63;

    // stage wT_swz -> LDS: 4 iters x 8 waves x (64 lanes x 16B) = 32 KB
    #pragma unroll
    for (int j = 0; j < 4; ++j) {
        int off = j * 8192 + wid * 1024;  // bytes; wave-uniform LDS base
        __builtin_amdgcn_global_load_lds(
            (const __attribute__((address_space(1))) void*)((const char*)wTs + off + lane * 16),
            (__attribute__((address_space(3))) void*)((char*)wt + off),
            16, 0, 0);
    }

    const int qlo = lane & 15;   // MFMA col / A row index
    const int qhi = lane >> 4;   // 0..3, selects k-group of 8
    const int bid = blockIdx.x;
    const int b   = bid >> 7;    // 128 blocks per batch
    const int nb  = bid & 127;
    const int n0  = nb * NPB + wid * 32;  // this wave's n start (32 n per wave)

    f32x4 acc[8][2];
    #pragma unroll
    for (int i = 0; i < 8; ++i)
        #pragma unroll
        for (int j = 0; j < 2; ++j)
            acc[i][j] = (f32x4)0.0f;

    const float* in_base = input + ((size_t)b * N_ + n0) * CAT_;

    __syncthreads();

    #pragma unroll
    for (int ck = 0; ck < 4; ++ck) {
        bf16x8 bfrag[2];
        #pragma unroll
        for (int nt = 0; nt < 2; ++nt) {
            const float* p = in_base + (size_t)(nt * 16 + qlo) * CAT_ + ck * 32 + qhi * 8;
            f32x4 v0 = *(const f32x4*)p;
            f32x4 v1 = *(const f32x4*)(p + 4);
            bf16x8 t;
            #pragma unroll
            for (int e = 0; e < 4; ++e) {
                t[e]     = (__bf16)v0[e];
                t[e + 4] = (__bf16)v1[e];
            }
            bfrag[nt] = t;
        }
        const int cswz = (ck * 32 + qhi * 8) ^ ((qlo & 7) << 3);  // swizzled c-offset
        #pragma unroll
        for (int mt = 0; mt < 8; ++mt) {
            bf16x8 af = *(const bf16x8*)&wt[(mt * 16 + qlo) * CAT_ + cswz];
            acc[mt][0] = __builtin_amdgcn_mfma_f32_16x16x32_bf16(af, bfrag[0], acc[mt][0], 0, 0, 0);
            acc[mt][1] = __builtin_amdgcn_mfma_f32_16x16x32_bf16(af, bfrag[1], acc[mt][1], 0, 0, 0);
        }
    }

    // epilogue: C/D layout col=lane&15 -> n, row=(lane>>4)*4+reg -> f (m89/m91)
    float* outp = out + (size_t)b * FEAT_ * N_ + n0;
    #pragma unroll
    for (int mt = 0; mt < 8; ++mt) {
        #pragma unroll
        for (int nt = 0; nt < 2; ++nt) {
            #pragma unroll
            for (int r = 0; r < 4; ++r) {
                int f = mt * 16 + qhi * 4 + r;
                outp[(size_t)f * N_ + nt * 16 + qlo] = acc[mt][nt][r];
            }
        }
    }
}

// ---------------------------------------------------------------------------
// Fallback (R1 kernel): single launch with per-block LDS staging, used only
// if the workspace is too small for wT_swz.
// ---------------------------------------------------------------------------
constexpr int LDSTR = 136;
constexpr int FB_BLOCKS = (B_ * N_) / 128;  // 2048

__global__ __launch_bounds__(256, 4) void ocm_fused(
    const float* __restrict__ input,
    const float* __restrict__ weight,
    const int* __restrict__ keys,
    const float* __restrict__ values,
    float* __restrict__ out)
{
    const int bid = blockIdx.x;
    const int tid = threadIdx.x;

    if (bid >= FB_BLOCKS) {
        float* outw = out + (size_t)B_ * FEAT_ * N_;
        const int r = bid - FB_BLOCKS;
        bool keyed = false;
        for (int i = 0; i < K_; ++i) keyed |= (keys[i] == r);
        if (!keyed && tid < FEAT_)
            outw[r * FEAT_ + tid] = weight[r * FEAT_ + tid];
        if (r < K_ && tid < 64) {
            const int key = keys[r];
            float a0 = DELTA_ * weight[key * FEAT_ + tid]      + (1.0f - DELTA_) * values[r * FEAT_ + tid];
            float a1 = DELTA_ * weight[key * FEAT_ + tid + 64] + (1.0f - DELTA_) * values[r * FEAT_ + tid + 64];
            float ss = a0 * a0 + a1 * a1;
            #pragma unroll
            for (int off = 32; off > 0; off >>= 1)
                ss += __shfl_down(ss, off, 64);
            float nrm = sqrtf(__shfl(ss, 0, 64));
            outw[key * FEAT_ + tid]      = nrm;
            outw[key * FEAT_ + tid + 64] = nrm;
        }
        return;
    }

    __shared__ __bf16 wt[FEAT_ * LDSTR];
    #pragma unroll
    for (int j = 0; j < (CAT_ * FEAT_) / 256; ++j) {
        int i = tid + j * 256;
        int c = i >> 7;
        int f = i & (FEAT_ - 1);
        wt[f * LDSTR + c] = (__bf16)weight[i];
    }
    __syncthreads();

    const int wid  = tid >> 6;
    const int lane = tid & 63;
    const int qlo  = lane & 15;
    const int qhi  = lane >> 4;
    const int b    = bid >> 8;
    const int nb   = bid & 255;
    const int n0   = nb * 128 + wid * 32;

    f32x4 acc[8][2];
    #pragma unroll
    for (int i = 0; i < 8; ++i)
        #pragma unroll
        for (int j = 0; j < 2; ++j)
            acc[i][j] = (f32x4)0.0f;

    const float* in_base = input + ((size_t)b * N_ + n0) * CAT_;

    #pragma unroll
    for (int ck = 0; ck < 4; ++ck) {
        bf16x8 bfrag[2];
        #pragma unroll
        for (int nt = 0; nt < 2; ++nt) {
            const float* p = in_base + (size_t)(nt * 16 + qlo) * CAT_ + ck * 32 + qhi * 8;
            f32x4 v0 = *(const f32x4*)p;
            f32x4 v1 = *(const f32x4*)(p + 4);
            bf16x8 t;
            t[0] = (__bf16)v0[0]; t[1] = (__bf16)v0[1]; t[2] = (__bf16)v0[2]; t[3] = (__bf16)v0[3];
            t[4] = (__bf16)v1[0]; t[5] = (__bf16)v1[1]; t[6] = (__bf16)v1[2]; t[7] = (__bf16)v1[3];
            bfrag[nt] = t;
        }
        #pragma unroll
        for (int mt = 0; mt < 8; ++mt) {
            bf16x8 afrag = *(const bf16x8*)&wt[(mt * 16 + qlo) * LDSTR + ck * 32 + qhi * 8];
            acc[mt][0] = __builtin_amdgcn_mfma_f32_16x16x32_bf16(afrag, bfrag[0], acc[mt][0], 0, 0, 0);
            acc[mt][1] = __builtin_amdgcn_mfma_f32_16x16x32_bf16(afrag, bfrag[1], acc[mt][1], 0, 0, 0);
        }
    }

    float* outp = out + (size_t)b * FEAT_ * N_ + n0;
    #pragma unroll
    for (int mt = 0; mt < 8; ++mt) {
        #pragma unroll
        for (int nt = 0; nt < 2; ++nt) {
            #pragma unroll
            for (int r = 0; r < 4; ++r) {
                int f = mt * 16 + qhi * 4 + r;
                outp[(size_t)f * N_ + nt * 16 + qlo] = acc[mt][nt][r];
            }
        }
    }
}

extern "C" void kernel_launch(void* const* d_in, const int* in_sizes, int n_in,
                              void* d_out, int out_size, void* d_ws, size_t ws_size,
                              hipStream_t stream) {
    const float* input  = (const float*)d_in[0];
    const float* weight = (const float*)d_in[1];
    const int*   keys   = (const int*)d_in[2];
    const float* values = (const float*)d_in[3];
    float* out = (float*)d_out;

    if (ws_size >= (size_t)CAT_ * FEAT_ * sizeof(__bf16)) {
        __bf16* wTs = (__bf16*)d_ws;
        float* outw = out + (size_t)B_ * FEAT_ * N_;
        prep_kernel<<<CAT_, FEAT_, 0, stream>>>(weight, keys, values, outw, wTs);
        gemm_kernel<<<GEMM_BLOCKS, BLOCK, 0, stream>>>(input, wTs, out);
    } else {
        ocm_fused<<<FB_BLOCKS + CAT_, 256, 0, stream>>>(input, weight, keys, values, out);
    }
}

// Round 8
// 51.868 us; speedup vs baseline: 1.3053x; 1.0368x over previous
//
#include <hip/hip_runtime.h>
#include <math.h>

// Problem constants (from reference setup_inputs)
constexpr int B_ = 8, N_ = 32768, CAT_ = 128, FEAT_ = 128, K_ = 64;
constexpr float DELTA_ = 0.5f;

typedef __bf16 bf16x8 __attribute__((ext_vector_type(8)));
typedef float f32x4 __attribute__((ext_vector_type(4)));
typedef float f32x16 __attribute__((ext_vector_type(16)));

constexpr int BLOCK = 512;                       // 8 waves share one weight tile
constexpr int NPB   = 256;                       // n-rows per block (32 per wave)
constexpr int GEMM_BLOCKS = (B_ * N_) / NPB;     // 1024

// ---------------------------------------------------------------------------
// prep: builds bf16 W^T [FEAT][CAT], XOR-swizzled within each row
// (wT_swz[f][c ^ ((f&7)<<3)] = w[c][f]) so a LINEAR global_load_lds copy
// yields a swizzled LDS image (G21). Also produces new_weight.
// grid = CAT_ blocks x FEAT_ threads.
// ---------------------------------------------------------------------------
__global__ void prep_kernel(const float* __restrict__ weight,
                            const int* __restrict__ keys,
                            const float* __restrict__ values,
                            float* __restrict__ outw,    // [CAT][FEAT]
                            __bf16* __restrict__ wTs)    // [FEAT][CAT] swizzled
{
    const int r = blockIdx.x;    // weight row (CAT index = c)
    const int t = threadIdx.x;   // FEAT index (f)
    float w = weight[r * FEAT_ + t];
    wTs[t * CAT_ + (r ^ ((t & 7) << 3))] = (__bf16)w;

    bool keyed = false;
    for (int i = 0; i < K_; ++i) keyed |= (keys[i] == r);
    if (!keyed) outw[r * FEAT_ + t] = w;

    if (r < K_ && t < 64) {
        const int key = keys[r];
        float a0 = DELTA_ * weight[key * FEAT_ + t]      + (1.0f - DELTA_) * values[r * FEAT_ + t];
        float a1 = DELTA_ * weight[key * FEAT_ + t + 64] + (1.0f - DELTA_) * values[r * FEAT_ + t + 64];
        float ss = a0 * a0 + a1 * a1;
        #pragma unroll
        for (int off = 32; off > 0; off >>= 1)
            ss += __shfl_down(ss, off, 64);
        float nrm = sqrtf(__shfl(ss, 0, 64));
        outw[key * FEAT_ + t]      = nrm;
        outw[key * FEAT_ + t + 64] = nrm;
    }
}

// ---------------------------------------------------------------------------
// gemm (32x32x16 MFMA): out[b][f][n] = sum_c input[b][n][c] * w[c][f]
//  - 8 waves share ONE 32KB LDS weight tile (global_load_lds staged)
//  - A = weight (row=f: lane&31), B = input (col=n: lane&31),
//    k = (lane>>5)*8 + e per K=16 step
//  - D layout (m74/m101 verified): col=lane&31 -> n, row=(reg&3)+8*(reg>>2)
//    +4*(lane>>5) -> f. Store instr = lanes 0-31 one FULL 128B line at f,
//    lanes 32-63 another at f+4 -> nontemporal stores are full-line streams:
//    no L3 allocation, input stays L3-resident across graph replays.
//    (R4's nt failure = 64B partial lines; this is the fix, not a retry.)
// ---------------------------------------------------------------------------
__global__ __launch_bounds__(BLOCK, 2) void gemm_kernel(
    const float* __restrict__ input,   // [B][N][CAT]
    const __bf16* __restrict__ wTs,    // [FEAT][CAT] bf16, swizzled
    float* __restrict__ out)           // [B][FEAT][N]
{
    __shared__ __bf16 wt[FEAT_ * CAT_];  // 32 KB, linear copy of wTs (pre-swizzled)

    const int tid  = threadIdx.x;
    const int wid  = tid >> 6;           // 0..7
    const int lane = tid & 63;

    // stage wT_swz -> LDS: 4 iters x 8 waves x (64 lanes x 16B) = 32 KB
    #pragma unroll
    for (int j = 0; j < 4; ++j) {
        int off = j * 8192 + wid * 1024;  // bytes; wave-uniform LDS base
        __builtin_amdgcn_global_load_lds(
            (const __attribute__((address_space(1))) void*)((const char*)wTs + off + lane * 16),
            (__attribute__((address_space(3))) void*)((char*)wt + off),
            16, 0, 0);
    }

    const int nl = lane & 31;    // n within wave tile / f within mt tile
    const int kg = lane >> 5;    // 0..1, k-group of 8
    const int bid = blockIdx.x;
    const int b   = bid >> 7;    // 128 blocks per batch
    const int nb  = bid & 127;
    const int n0  = nb * NPB + wid * 32;  // this wave's n start (32 n per wave)

    f32x16 acc[4];
    #pragma unroll
    for (int i = 0; i < 4; ++i)
        acc[i] = (f32x16)0.0f;

    const float* inp = input + ((size_t)b * N_ + n0 + nl) * CAT_;

    __syncthreads();

    #pragma unroll
    for (int ck = 0; ck < 8; ++ck) {     // K-steps of 16
        const int c0 = ck * 16 + kg * 8;
        f32x4 v0 = *(const f32x4*)(inp + c0);
        f32x4 v1 = *(const f32x4*)(inp + c0 + 4);
        bf16x8 bfrag;
        #pragma unroll
        for (int e = 0; e < 4; ++e) {
            bfrag[e]     = (__bf16)v0[e];
            bfrag[e + 4] = (__bf16)v1[e];
        }
        #pragma unroll
        for (int mt = 0; mt < 4; ++mt) { // 4 f subtiles of 32
            const int f = mt * 32 + nl;
            bf16x8 af = *(const bf16x8*)&wt[f * CAT_ + (c0 ^ ((f & 7) << 3))];
            acc[mt] = __builtin_amdgcn_mfma_f32_32x32x16_bf16(af, bfrag, acc[mt], 0, 0, 0);
        }
    }

    // epilogue: nontemporal full-line stores
    float* outp = out + (size_t)b * FEAT_ * N_ + n0 + nl;
    #pragma unroll
    for (int mt = 0; mt < 4; ++mt) {
        #pragma unroll
        for (int r = 0; r < 16; ++r) {
            const int f = mt * 32 + (r & 3) + 8 * (r >> 2) + 4 * kg;
            __builtin_nontemporal_store(acc[mt][r], outp + (size_t)f * N_);
        }
    }
}

// ---------------------------------------------------------------------------
// Fallback (R1 kernel): single launch with per-block LDS staging, used only
// if the workspace is too small for wT_swz.
// ---------------------------------------------------------------------------
constexpr int LDSTR = 136;
constexpr int FB_BLOCKS = (B_ * N_) / 128;  // 2048

__global__ __launch_bounds__(256, 4) void ocm_fused(
    const float* __restrict__ input,
    const float* __restrict__ weight,
    const int* __restrict__ keys,
    const float* __restrict__ values,
    float* __restrict__ out)
{
    const int bid = blockIdx.x;
    const int tid = threadIdx.x;

    if (bid >= FB_BLOCKS) {
        float* outw = out + (size_t)B_ * FEAT_ * N_;
        const int r = bid - FB_BLOCKS;
        bool keyed = false;
        for (int i = 0; i < K_; ++i) keyed |= (keys[i] == r);
        if (!keyed && tid < FEAT_)
            outw[r * FEAT_ + tid] = weight[r * FEAT_ + tid];
        if (r < K_ && tid < 64) {
            const int key = keys[r];
            float a0 = DELTA_ * weight[key * FEAT_ + tid]      + (1.0f - DELTA_) * values[r * FEAT_ + tid];
            float a1 = DELTA_ * weight[key * FEAT_ + tid + 64] + (1.0f - DELTA_) * values[r * FEAT_ + tid + 64];
            float ss = a0 * a0 + a1 * a1;
            #pragma unroll
            for (int off = 32; off > 0; off >>= 1)
                ss += __shfl_down(ss, off, 64);
            float nrm = sqrtf(__shfl(ss, 0, 64));
            outw[key * FEAT_ + tid]      = nrm;
            outw[key * FEAT_ + tid + 64] = nrm;
        }
        return;
    }

    __shared__ __bf16 wt[FEAT_ * LDSTR];
    #pragma unroll
    for (int j = 0; j < (CAT_ * FEAT_) / 256; ++j) {
        int i = tid + j * 256;
        int c = i >> 7;
        int f = i & (FEAT_ - 1);
        wt[f * LDSTR + c] = (__bf16)weight[i];
    }
    __syncthreads();

    const int wid  = tid >> 6;
    const int lane = tid & 63;
    const int qlo  = lane & 15;
    const int qhi  = lane >> 4;
    const int b    = bid >> 8;
    const int nb   = bid & 255;
    const int n0   = nb * 128 + wid * 32;

    f32x4 acc[8][2];
    #pragma unroll
    for (int i = 0; i < 8; ++i)
        #pragma unroll
        for (int j = 0; j < 2; ++j)
            acc[i][j] = (f32x4)0.0f;

    const float* in_base = input + ((size_t)b * N_ + n0) * CAT_;

    #pragma unroll
    for (int ck = 0; ck < 4; ++ck) {
        bf16x8 bfrag[2];
        #pragma unroll
        for (int nt = 0; nt < 2; ++nt) {
            const float* p = in_base + (size_t)(nt * 16 + qlo) * CAT_ + ck * 32 + qhi * 8;
            f32x4 v0 = *(const f32x4*)p;
            f32x4 v1 = *(const f32x4*)(p + 4);
            bf16x8 t;
            t[0] = (__bf16)v0[0]; t[1] = (__bf16)v0[1]; t[2] = (__bf16)v0[2]; t[3] = (__bf16)v0[3];
            t[4] = (__bf16)v1[0]; t[5] = (__bf16)v1[1]; t[6] = (__bf16)v1[2]; t[7] = (__bf16)v1[3];
            bfrag[nt] = t;
        }
        #pragma unroll
        for (int mt = 0; mt < 8; ++mt) {
            bf16x8 afrag = *(const bf16x8*)&wt[(mt * 16 + qlo) * LDSTR + ck * 32 + qhi * 8];
            acc[mt][0] = __builtin_amdgcn_mfma_f32_16x16x32_bf16(afrag, bfrag[0], acc[mt][0], 0, 0, 0);
            acc[mt][1] = __builtin_amdgcn_mfma_f32_16x16x32_bf16(afrag, bfrag[1], acc[mt][1], 0, 0, 0);
        }
    }

    float* outp = out + (size_t)b * FEAT_ * N_ + n0;
    #pragma unroll
    for (int mt = 0; mt < 8; ++mt) {
        #pragma unroll
        for (int nt = 0; nt < 2; ++nt) {
            #pragma unroll
            for (int r = 0; r < 4; ++r) {
                int f = mt * 16 + qhi * 4 + r;
                outp[(size_t)f * N_ + nt * 16 + qlo] = acc[mt][nt][r];
            }
        }
    }
}

extern "C" void kernel_launch(void* const* d_in, const int* in_sizes, int n_in,
                              void* d_out, int out_size, void* d_ws, size_t ws_size,
                              hipStream_t stream) {
    const float* input  = (const float*)d_in[0];
    const float* weight = (const float*)d_in[1];
    const int*   keys   = (const int*)d_in[2];
    const float* values = (const float*)d_in[3];
    float* out = (float*)d_out;

    if (ws_size >= (size_t)CAT_ * FEAT_ * sizeof(__bf16)) {
        __bf16* wTs = (__bf16*)d_ws;
        float* outw = out + (size_t)B_ * FEAT_ * N_;
        prep_kernel<<<CAT_, FEAT_, 0, stream>>>(weight, keys, values, outw, wTs);
        gemm_kernel<<<GEMM_BLOCKS, BLOCK, 0, stream>>>(input, wTs, out);
    } else {
        ocm_fused<<<FB_BLOCKS + CAT_, 256, 0, stream>>>(input, weight, keys, values, out);
    }
}